// Round 9
// baseline (523.330 us; speedup 1.0000x reference)
//
#include <hip/hip_runtime.h>

// GRU4Rec fused, round 9: r5 numerics + v_fma_mix_f32 inline asm.
//
// r7/r8 bit-identical failures exonerated pack_pair and condemned the fdot2
// path (gfx950 lowering unverified; abandoned). r5 (PASSED, 2.44e-4) was
// VALU-bloated: (float)w16 emitted extract+cvt+fma (~650 instr/step,
// busy 199us). This round keeps r5's exact semantics (fp32 h readlane
// broadcast, fp32 accumulate, same accumulation order) but consumes packed
// fp16 weight dwords directly with v_fma_mix_f32 (op_sel picks the half):
// 192 fma_mix + 64 readlane per step ~= 274 instr, 2.4x fewer.
//
// Structure (proven r5): P table fp16 (38.4 MB, L3-resident), wave-per-row
// scan, counting-sort + snake pairing, prefetch 2 deep.
//
// Shapes: B=4096, T=200, H=64, V=100000. Output fp32.

#define T_SEQ 200
#define HD 64
#define VOCAB 100000
#define RPB 16    // vocab rows per proj block
#define PROW 192  // halves per P row: [0,128) = (r,z) pairs, [128,192) = n

typedef float v16f __attribute__((ext_vector_type(16)));
typedef _Float16 v16h __attribute__((ext_vector_type(16)));
typedef _Float16 h2v __attribute__((ext_vector_type(2)));
typedef unsigned v8u __attribute__((ext_vector_type(8)));

__device__ __forceinline__ float bcast(float v, int lane) {
  return __int_as_float(__builtin_amdgcn_readlane(__float_as_int(v), lane));
}

__device__ __forceinline__ float fsigmoid(float x) {
  float e = __builtin_amdgcn_exp2f(x * -1.442695040888963f);
  return __builtin_amdgcn_rcpf(1.0f + e);
}

__device__ __forceinline__ float ftanh(float x) {
  float e = __builtin_amdgcn_exp2f(x * -2.885390081777927f);
  return fmaf(2.0f, __builtin_amdgcn_rcpf(1.0f + e), -1.0f);
}

__device__ __forceinline__ unsigned pack_h2(float a, float b) {
  unsigned short lo = __builtin_bit_cast(unsigned short, (_Float16)a);
  unsigned short hi = __builtin_bit_cast(unsigned short, (_Float16)b);
  return (unsigned)lo | ((unsigned)hi << 16);
}

// acc += (fp32)(low fp16 half of wpk) * hk   — single full-rate VOP3P op.
__device__ __forceinline__ void fma_mix_lo(float& acc, unsigned wpk, float hk) {
  asm("v_fma_mix_f32 %0, %1, %2, %0 op_sel_hi:[1,0,0]"
      : "+v"(acc)
      : "v"(wpk), "s"(hk));
}
// acc += (fp32)(high fp16 half of wpk) * hk
__device__ __forceinline__ void fma_mix_hi(float& acc, unsigned wpk, float hk) {
  asm("v_fma_mix_f32 %0, %1, %2, %0 op_sel:[1,0,0] op_sel_hi:[1,0,0]"
      : "+v"(acc)
      : "v"(wpk), "s"(hk));
}

// One 16-wide K-chunk of the three gate dot products. src broadcast from
// lane base+k via readlane (fp32, exact r5 semantics); weight pair dword
// consumed in place by v_fma_mix_f32.
#define GH_CHUNK_MIX(cr, cz, cn, src, base, ar, az, an)  \
  do {                                                   \
    _Pragma("unroll")                                    \
    for (int j_ = 0; j_ < 8; ++j_) {                     \
      float h0_ = bcast((src), (base) + 2 * j_);         \
      float h1_ = bcast((src), (base) + 2 * j_ + 1);     \
      fma_mix_lo(ar, (cr)[j_], h0_);                     \
      fma_mix_lo(az, (cz)[j_], h0_);                     \
      fma_mix_lo(an, (cn)[j_], h0_);                     \
      fma_mix_hi(ar, (cr)[j_], h1_);                     \
      fma_mix_hi(az, (cz)[j_], h1_);                     \
      fma_mix_hi(an, (cn)[j_], h1_);                     \
    }                                                    \
  } while (0)

// Load one 64-wide fp32 row of W (row-major [192][64]) as 4 chunks of
// 8 packed fp16 pairs each (dword j = halves 2j,2j+1 -> w[2j],w[2j+1]).
#define LOAD_ROW_F16(W, row, c0, c1, c2, c3)                               \
  do {                                                                     \
    const v16f* p_ = reinterpret_cast<const v16f*>((W) + (size_t)(row)*HD);\
    c0 = __builtin_bit_cast(v8u, __builtin_convertvector(p_[0], v16h));    \
    c1 = __builtin_bit_cast(v8u, __builtin_convertvector(p_[1], v16h));    \
    c2 = __builtin_bit_cast(v8u, __builtin_convertvector(p_[2], v16h));    \
    c3 = __builtin_bit_cast(v8u, __builtin_convertvector(p_[3], v16h));    \
  } while (0)

// --------------------------------------------------- length sort (1 block)
__global__ __launch_bounds__(256) void sort_kernel(
    const int* __restrict__ seq_pos, int* __restrict__ order, int B) {
  __shared__ int hist[T_SEQ + 1];
  __shared__ int off[T_SEQ + 1];
  const int tid = threadIdx.x;
  for (int l = tid; l <= T_SEQ; l += 256) hist[l] = 0;
  __syncthreads();
  for (int b = tid; b < B; b += 256) {
    int L = seq_pos[b]; L = L < 1 ? 1 : (L > T_SEQ ? T_SEQ : L);
    atomicAdd(&hist[L], 1);
  }
  __syncthreads();
  if (tid == 0) {
    int run = 0;
    for (int l = T_SEQ; l >= 1; --l) { off[l] = run; run += hist[l]; }
  }
  __syncthreads();
  for (int b = tid; b < B; b += 256) {
    int L = seq_pos[b]; L = L < 1 ? 1 : (L > T_SEQ ? T_SEQ : L);
    int pos = atomicAdd(&off[L], 1);
    order[pos] = b;  // descending length
  }
}

// --------------------------------------------------- phase 1: P = W_ih @ emb
__global__ __launch_bounds__(64) void gru_proj_kernel(
    const float* __restrict__ emb, const float* __restrict__ W_ih,
    _Float16* __restrict__ P16) {
  const int i = threadIdx.x;
  const int v0 = blockIdx.x * RPB;

  v8u r0, r1, r2, r3, z0, z1, z2, z3, n0, n1, n2, n3;
  LOAD_ROW_F16(W_ih, i, r0, r1, r2, r3);
  LOAD_ROW_F16(W_ih, HD + i, z0, z1, z2, z3);
  LOAD_ROW_F16(W_ih, 2 * HD + i, n0, n1, n2, n3);

  float x[RPB];
#pragma unroll
  for (int r = 0; r < RPB; ++r)
    x[r] = emb[(size_t)(v0 + r) * HD + i];  // lane i holds emb[v][i]

#pragma unroll 4
  for (int r = 0; r < RPB; ++r) {
    float ar0 = 0.f, az0 = 0.f, an0 = 0.f;
    float ar1 = 0.f, az1 = 0.f, an1 = 0.f;
    GH_CHUNK_MIX(r0, z0, n0, x[r], 0, ar0, az0, an0);
    GH_CHUNK_MIX(r1, z1, n1, x[r], 16, ar1, az1, an1);
    GH_CHUNK_MIX(r2, z2, n2, x[r], 32, ar0, az0, an0);
    GH_CHUNK_MIX(r3, z3, n3, x[r], 48, ar1, az1, an1);

    _Float16* Prow = P16 + (size_t)(v0 + r) * PROW;
    reinterpret_cast<unsigned*>(Prow)[i] = pack_h2(ar0 + ar1, az0 + az1);
    Prow[128 + i] = (_Float16)(an0 + an1);
  }
}

// --------------------------------------------------- phase 2: recurrent scan
__global__ __launch_bounds__(64) void gru_scan_kernel(
    const int* __restrict__ seq_token, const int* __restrict__ seq_pos,
    const _Float16* __restrict__ P16, const float* __restrict__ W_hh,
    float* __restrict__ out, const int* __restrict__ order, int use_order,
    int B) {
  const int i = threadIdx.x;
  const int g = blockIdx.x;

  v8u r0, r1, r2, r3, z0, z1, z2, z3, n0, n1, n2, n3;
  LOAD_ROW_F16(W_hh, i, r0, r1, r2, r3);
  LOAD_ROW_F16(W_hh, HD + i, z0, z1, z2, z3);
  LOAD_ROW_F16(W_hh, 2 * HD + i, n0, n1, n2, n3);

#pragma unroll 1
  for (int js = 0; js < 2; ++js) {
    const int j = js ? (B - 1 - g) : g;
    const int b = use_order ? order[j] : j;

    int L = seq_pos[b];
    L = L < 1 ? 1 : (L > T_SEQ ? T_SEQ : L);
    const int* tok = seq_token + (size_t)b * T_SEQ;

    int t0 = tok[0];
    const _Float16* Pr0 = P16 + (size_t)t0 * PROW;
    h2v rz0 = __builtin_bit_cast(h2v, reinterpret_cast<const unsigned*>(Pr0)[i]);
    float pr = (float)rz0[0], pz = (float)rz0[1];
    float pn = (float)Pr0[128 + i];
    int tk1 = (L > 1) ? tok[1] : 0;

    float h = 0.f;
    for (int t = 0; t < L; ++t) {
      // Prefetch next step's P row (token already resident) + token t+2.
      unsigned u_rz = 0;
      _Float16 u_n = (_Float16)0.f;
      if (t + 1 < L) {
        const _Float16* Pn = P16 + (size_t)tk1 * PROW;
        u_rz = reinterpret_cast<const unsigned*>(Pn)[i];
        u_n = Pn[128 + i];
      }
      int tk2 = (t + 2 < L) ? tok[t + 2] : 0;

      // gh = W_hh rows {i,64+i,128+i} . h ; fp32 h broadcast via readlane,
      // packed fp16 weights consumed in place by v_fma_mix_f32.
      float ar0 = 0.f, az0 = 0.f, an0 = 0.f;
      float ar1 = 0.f, az1 = 0.f, an1 = 0.f;
      GH_CHUNK_MIX(r0, z0, n0, h, 0, ar0, az0, an0);
      GH_CHUNK_MIX(r1, z1, n1, h, 16, ar1, az1, an1);
      GH_CHUNK_MIX(r2, z2, n2, h, 32, ar0, az0, an0);
      GH_CHUNK_MIX(r3, z3, n3, h, 48, ar1, az1, an1);

      float r = fsigmoid(pr + ar0 + ar1);
      float z = fsigmoid(pz + az0 + az1);
      float n = ftanh(fmaf(r, an0 + an1, pn));
      h = fmaf(z, h - n, n);  // (1-z)*n + z*h

      h2v nrz = __builtin_bit_cast(h2v, u_rz);
      pr = (float)nrz[0];
      pz = (float)nrz[1];
      pn = (float)u_n;
      tk1 = tk2;
    }

    out[(size_t)b * HD + i] = h;
  }
}

extern "C" void kernel_launch(void* const* d_in, const int* in_sizes, int n_in,
                              void* d_out, int out_size, void* d_ws, size_t ws_size,
                              hipStream_t stream) {
  const int* seq_token = (const int*)d_in[0];   // [B, T] int32
  const int* seq_pos   = (const int*)d_in[1];   // [B] int32
  const float* emb     = (const float*)d_in[2]; // [V, H]
  const float* W_ih    = (const float*)d_in[3]; // [3H, H]
  const float* W_hh    = (const float*)d_in[4]; // [3H, H]
  float* out = (float*)d_out;                   // [B, H] fp32

  const int B = in_sizes[1];                    // 4096

  _Float16* P16 = (_Float16*)d_ws;              // 38.4 MB
  const size_t pbytes = ((size_t)VOCAB * PROW * 2 + 255) & ~(size_t)255;
  int* order = (int*)((char*)d_ws + pbytes);
  const int use_order = (ws_size >= pbytes + (size_t)B * 4) ? 1 : 0;

  if (use_order) sort_kernel<<<1, 256, 0, stream>>>(seq_pos, order, B);
  gru_proj_kernel<<<VOCAB / RPB, 64, 0, stream>>>(emb, W_ih, P16);
  gru_scan_kernel<<<B / 2, 64, 0, stream>>>(seq_token, seq_pos, P16, W_hh, out,
                                            order, use_order, B);
}

// Round 10
// 449.811 us; speedup vs baseline: 1.1634x; 1.1634x over previous
//
#include <hip/hip_runtime.h>

// GRU4Rec fused, round 10: dual-row lockstep scan, r5-proven codegen.
//
// Evidence r1/r2/r3/r9: any "clever" weight consumption (fp32 arrays,
// waves_per_eu, inline-asm fma_mix) makes the RA demote weights
// (VGPR_Count 80-108 < the 96-192 needed) and inject per-use copies.
// r5 (VGPR=144) is the ONE configuration with weights resident:
// v16h chunks + (float)extract + fmaf. Keep that codegen exactly.
//
// Optimization here is architectural: one wave advances TWO sorted-adjacent
// batch rows in lockstep, so the 192 weight cvts per step are shared:
// 192 cvt + 384 fma + 128 readlane ~= 770 instr / 2 rows (was 594/row).
// Snake over pair indices keeps ~201 steps/wave. Short row's h frozen by
// a wave-uniform select once t >= Lb. Proj: 8 rows share each cvt.
//
// Shapes: B=4096, T=200, H=64, V=100000. Output fp32.

#define T_SEQ 200
#define HD 64
#define VOCAB 100000
#define RPB 16    // vocab rows per proj block
#define PROW 192  // halves per P row: [0,128) = (r,z) pairs, [128,192) = n

typedef float v16f __attribute__((ext_vector_type(16)));
typedef _Float16 v16h __attribute__((ext_vector_type(16)));
typedef _Float16 h2v __attribute__((ext_vector_type(2)));

__device__ __forceinline__ float bcast(float v, int lane) {
  return __int_as_float(__builtin_amdgcn_readlane(__float_as_int(v), lane));
}

__device__ __forceinline__ float fsigmoid(float x) {
  float e = __builtin_amdgcn_exp2f(x * -1.442695040888963f);
  return __builtin_amdgcn_rcpf(1.0f + e);
}

__device__ __forceinline__ float ftanh(float x) {
  float e = __builtin_amdgcn_exp2f(x * -2.885390081777927f);
  return fmaf(2.0f, __builtin_amdgcn_rcpf(1.0f + e), -1.0f);
}

__device__ __forceinline__ unsigned pack_h2(float a, float b) {
  unsigned short lo = __builtin_bit_cast(unsigned short, (_Float16)a);
  unsigned short hi = __builtin_bit_cast(unsigned short, (_Float16)b);
  return (unsigned)lo | ((unsigned)hi << 16);
}

// Load one 64-wide fp32 row of W (row-major [192][64]) as 4 fp16 chunks.
#define LOAD_ROW_F16(W, row, c0, c1, c2, c3)                               \
  do {                                                                     \
    const v16f* p_ = reinterpret_cast<const v16f*>((W) + (size_t)(row)*HD);\
    c0 = __builtin_convertvector(p_[0], v16h);                             \
    c1 = __builtin_convertvector(p_[1], v16h);                             \
    c2 = __builtin_convertvector(p_[2], v16h);                             \
    c3 = __builtin_convertvector(p_[3], v16h);                             \
  } while (0)

// 16 K-steps of the 3 gate dot products for TWO rows, sharing the cvts.
#define GH2_CHUNK(cr, cz, cn, ha, hb, base, Ar, Az, An, Br, Bz, Bn)   \
  do {                                                                \
    _Pragma("unroll")                                                 \
    for (int j_ = 0; j_ < 16; ++j_) {                                 \
      float fr_ = (float)(cr)[j_];                                    \
      float fz_ = (float)(cz)[j_];                                    \
      float fn_ = (float)(cn)[j_];                                    \
      float hak_ = bcast((ha), (base) + j_);                          \
      float hbk_ = bcast((hb), (base) + j_);                          \
      Ar = fmaf(fr_, hak_, Ar);                                       \
      Az = fmaf(fz_, hak_, Az);                                       \
      An = fmaf(fn_, hak_, An);                                       \
      Br = fmaf(fr_, hbk_, Br);                                       \
      Bz = fmaf(fz_, hbk_, Bz);                                       \
      Bn = fmaf(fn_, hbk_, Bn);                                       \
    }                                                                 \
  } while (0)

// Proj: 16 K-steps for EIGHT rows sharing the cvts (x0 = first row idx).
#define PJ_CHUNK(cr, cz, cn, x, x0, base, ar, az, an)                 \
  do {                                                                \
    _Pragma("unroll")                                                 \
    for (int j_ = 0; j_ < 16; ++j_) {                                 \
      float fr_ = (float)(cr)[j_];                                    \
      float fz_ = (float)(cz)[j_];                                    \
      float fn_ = (float)(cn)[j_];                                    \
      _Pragma("unroll")                                               \
      for (int r_ = 0; r_ < 8; ++r_) {                                \
        float xk_ = bcast((x)[(x0) + r_], (base) + j_);               \
        ar[r_] = fmaf(fr_, xk_, ar[r_]);                              \
        az[r_] = fmaf(fz_, xk_, az[r_]);                              \
        an[r_] = fmaf(fn_, xk_, an[r_]);                              \
      }                                                               \
    }                                                                 \
  } while (0)

// --------------------------------------------------- length sort (1 block)
__global__ __launch_bounds__(256) void sort_kernel(
    const int* __restrict__ seq_pos, int* __restrict__ order, int B) {
  __shared__ int hist[T_SEQ + 1];
  __shared__ int off[T_SEQ + 1];
  const int tid = threadIdx.x;
  for (int l = tid; l <= T_SEQ; l += 256) hist[l] = 0;
  __syncthreads();
  for (int b = tid; b < B; b += 256) {
    int L = seq_pos[b]; L = L < 1 ? 1 : (L > T_SEQ ? T_SEQ : L);
    atomicAdd(&hist[L], 1);
  }
  __syncthreads();
  if (tid == 0) {
    int run = 0;
    for (int l = T_SEQ; l >= 1; --l) { off[l] = run; run += hist[l]; }
  }
  __syncthreads();
  for (int b = tid; b < B; b += 256) {
    int L = seq_pos[b]; L = L < 1 ? 1 : (L > T_SEQ ? T_SEQ : L);
    int pos = atomicAdd(&off[L], 1);
    order[pos] = b;  // descending length
  }
}

// --------------------------------------------------- phase 1: P = W_ih @ emb
__global__ __launch_bounds__(64) void gru_proj_kernel(
    const float* __restrict__ emb, const float* __restrict__ W_ih,
    _Float16* __restrict__ P16) {
  const int i = threadIdx.x;
  const int v0 = blockIdx.x * RPB;

  v16h r0, r1, r2, r3, z0, z1, z2, z3, n0, n1, n2, n3;
  LOAD_ROW_F16(W_ih, i, r0, r1, r2, r3);
  LOAD_ROW_F16(W_ih, HD + i, z0, z1, z2, z3);
  LOAD_ROW_F16(W_ih, 2 * HD + i, n0, n1, n2, n3);

  float x[RPB];
#pragma unroll
  for (int r = 0; r < RPB; ++r)
    x[r] = emb[(size_t)(v0 + r) * HD + i];  // lane i holds emb[v][i]

#pragma unroll 1
  for (int g2 = 0; g2 < 2; ++g2) {
    float ar[8], az[8], an[8];
#pragma unroll
    for (int r = 0; r < 8; ++r) { ar[r] = 0.f; az[r] = 0.f; an[r] = 0.f; }

    PJ_CHUNK(r0, z0, n0, x, 8 * g2, 0, ar, az, an);
    PJ_CHUNK(r1, z1, n1, x, 8 * g2, 16, ar, az, an);
    PJ_CHUNK(r2, z2, n2, x, 8 * g2, 32, ar, az, an);
    PJ_CHUNK(r3, z3, n3, x, 8 * g2, 48, ar, az, an);

#pragma unroll
    for (int r = 0; r < 8; ++r) {
      _Float16* Prow = P16 + (size_t)(v0 + 8 * g2 + r) * PROW;
      reinterpret_cast<unsigned*>(Prow)[i] = pack_h2(ar[r], az[r]);
      Prow[128 + i] = (_Float16)an[r];
    }
  }
}

// --------------------------------------------------- phase 2: recurrent scan
// One wave advances TWO sorted-adjacent rows in lockstep; snake over pair
// indices for balance. 1024 blocks x 64 threads.
__global__ __launch_bounds__(64) void gru_scan_kernel(
    const int* __restrict__ seq_token, const int* __restrict__ seq_pos,
    const _Float16* __restrict__ P16, const float* __restrict__ W_hh,
    float* __restrict__ out, const int* __restrict__ order, int use_order,
    int B) {
  const int i = threadIdx.x;
  const int g = blockIdx.x;  // 0 .. B/4-1

  v16h r0, r1, r2, r3, z0, z1, z2, z3, n0, n1, n2, n3;
  LOAD_ROW_F16(W_hh, i, r0, r1, r2, r3);
  LOAD_ROW_F16(W_hh, HD + i, z0, z1, z2, z3);
  LOAD_ROW_F16(W_hh, 2 * HD + i, n0, n1, n2, n3);

#pragma unroll 1
  for (int js = 0; js < 2; ++js) {
    const int p = js ? (B / 2 - 1 - g) : g;  // pair index (snake)
    int a = use_order ? order[2 * p] : 2 * p;
    int b = use_order ? order[2 * p + 1] : 2 * p + 1;

    int La = seq_pos[a]; La = La < 1 ? 1 : (La > T_SEQ ? T_SEQ : La);
    int Lb = seq_pos[b]; Lb = Lb < 1 ? 1 : (Lb > T_SEQ ? T_SEQ : Lb);
    if (Lb > La) {  // ensure La >= Lb
      int tmp = a; a = b; b = tmp;
      tmp = La; La = Lb; Lb = tmp;
    }
    const int* toka = seq_token + (size_t)a * T_SEQ;
    const int* tokb = seq_token + (size_t)b * T_SEQ;

    const _Float16* Pa0 = P16 + (size_t)toka[0] * PROW;
    h2v rza = __builtin_bit_cast(h2v, reinterpret_cast<const unsigned*>(Pa0)[i]);
    float pra = (float)rza[0], pza = (float)rza[1];
    float pna = (float)Pa0[128 + i];
    const _Float16* Pb0 = P16 + (size_t)tokb[0] * PROW;
    h2v rzb = __builtin_bit_cast(h2v, reinterpret_cast<const unsigned*>(Pb0)[i]);
    float prb = (float)rzb[0], pzb = (float)rzb[1];
    float pnb = (float)Pb0[128 + i];

    int tka1 = (La > 1) ? toka[1] : 0;
    int tkb1 = (Lb > 1) ? tokb[1] : 0;

    float ha = 0.f, hb = 0.f;
    for (int t = 0; t < La; ++t) {
      // Prefetch next step's P rows (tokens already resident) + t+2 tokens.
      unsigned ua_rz = 0, ub_rz = 0;
      _Float16 ua_n = (_Float16)0.f, ub_n = (_Float16)0.f;
      if (t + 1 < La) {
        const _Float16* Pn = P16 + (size_t)tka1 * PROW;
        ua_rz = reinterpret_cast<const unsigned*>(Pn)[i];
        ua_n = Pn[128 + i];
      }
      if (t + 1 < Lb) {
        const _Float16* Pn = P16 + (size_t)tkb1 * PROW;
        ub_rz = reinterpret_cast<const unsigned*>(Pn)[i];
        ub_n = Pn[128 + i];
      }
      int tka2 = (t + 2 < La) ? toka[t + 2] : 0;
      int tkb2 = (t + 2 < Lb) ? tokb[t + 2] : 0;

      // Dual-row gh: weight cvts shared between rows a and b.
      float Ar = 0.f, Az = 0.f, An = 0.f;
      float Br = 0.f, Bz = 0.f, Bn = 0.f;
      GH2_CHUNK(r0, z0, n0, ha, hb, 0, Ar, Az, An, Br, Bz, Bn);
      GH2_CHUNK(r1, z1, n1, ha, hb, 16, Ar, Az, An, Br, Bz, Bn);
      GH2_CHUNK(r2, z2, n2, ha, hb, 32, Ar, Az, An, Br, Bz, Bn);
      GH2_CHUNK(r3, z3, n3, ha, hb, 48, Ar, Az, An, Br, Bz, Bn);

      float ra = fsigmoid(pra + Ar);
      float za = fsigmoid(pza + Az);
      float na = ftanh(fmaf(ra, An, pna));
      ha = fmaf(za, ha - na, na);  // row a always advances (t < La)

      float rb = fsigmoid(prb + Br);
      float zb = fsigmoid(pzb + Bz);
      float nb = ftanh(fmaf(rb, Bn, pnb));
      float hbn = fmaf(zb, hb - nb, nb);
      hb = (t < Lb) ? hbn : hb;  // wave-uniform freeze after Lb

      h2v na2 = __builtin_bit_cast(h2v, ua_rz);
      pra = (float)na2[0]; pza = (float)na2[1]; pna = (float)ua_n;
      h2v nb2 = __builtin_bit_cast(h2v, ub_rz);
      prb = (float)nb2[0]; pzb = (float)nb2[1]; pnb = (float)ub_n;
      tka1 = tka2; tkb1 = tkb2;
    }

    out[(size_t)a * HD + i] = ha;
    out[(size_t)b * HD + i] = hb;
  }
}

extern "C" void kernel_launch(void* const* d_in, const int* in_sizes, int n_in,
                              void* d_out, int out_size, void* d_ws, size_t ws_size,
                              hipStream_t stream) {
  const int* seq_token = (const int*)d_in[0];   // [B, T] int32
  const int* seq_pos   = (const int*)d_in[1];   // [B] int32
  const float* emb     = (const float*)d_in[2]; // [V, H]
  const float* W_ih    = (const float*)d_in[3]; // [3H, H]
  const float* W_hh    = (const float*)d_in[4]; // [3H, H]
  float* out = (float*)d_out;                   // [B, H] fp32

  const int B = in_sizes[1];                    // 4096

  _Float16* P16 = (_Float16*)d_ws;              // 38.4 MB
  const size_t pbytes = ((size_t)VOCAB * PROW * 2 + 255) & ~(size_t)255;
  int* order = (int*)((char*)d_ws + pbytes);
  const int use_order = (ws_size >= pbytes + (size_t)B * 4) ? 1 : 0;

  if (use_order) sort_kernel<<<1, 256, 0, stream>>>(seq_pos, order, B);
  gru_proj_kernel<<<VOCAB / RPB, 64, 0, stream>>>(emb, W_ih, P16);
  gru_scan_kernel<<<B / 4, 64, 0, stream>>>(seq_token, seq_pos, P16, W_hh, out,
                                            order, use_order, B);
}